// Round 5
// baseline (99.779 us; speedup 1.0000x reference)
//
#include <hip/hip_runtime.h>

#define B_TOT 4096
#define S_LEN 2048
#define K_CH  64                  // chunks per sequence == wave lanes
#define L_CH  32                  // steps per chunk
#define U_ROW 2056
#define O_ROW 2057
#define PROW  2121                // padded LDS row: idx(g) = g + (g>>5), max 2119

// One wave per batch, lane k owns chunk k. All global traffic coalesced via a
// per-wave padded LDS row (bank = (k + const) % 32 -> 2-way aliasing = free).
__global__ __launch_bounds__(256, 4) void arix_fused(
    const float* __restrict__ y, const float* __restrict__ u,
    const float* __restrict__ W, float* __restrict__ out)
{
    __shared__ float ubuf[4][PROW];
    __shared__ float Msh[6 * 64];  // level l: M_l[i][j] at Msh[l*64+i*8+j]
    __shared__ float Csh[6 * 8];
    const int lt = threadIdx.x;
    const int k  = lt & 63;                    // lane == chunk id
    const int w  = lt >> 6;
    const int b  = blockIdx.x * 4 + w;         // wave == batch

    float wd[8], wu[8];
#pragma unroll
    for (int j = 0; j < 8; ++j) { wd[j] = W[j]; wu[j] = W[8 + j]; }

    // ---- stage u row coalesced into padded LDS (per-wave buffer) ----
    const float4* up = (const float4*)(u + (long)b * U_ROW);  // 16B-aligned
    float* ub = ubuf[w];
#pragma unroll
    for (int r = 0; r < 8; ++r) {
        float4 v = up[r * 64 + k];
        const int g = (r * 64 + k) * 4;
        const int idx = g + (g >> 5);
        ub[idx] = v.x; ub[idx + 1] = v.y; ub[idx + 2] = v.z; ub[idx + 3] = v.w;
    }
    if (k < 2) {                                // floats 2048..2055
        float4 v = up[512 + k];
        const int g = (512 + k) * 4;
        const int idx = g + (g >> 5);
        ub[idx] = v.x; ub[idx + 1] = v.y; ub[idx + 2] = v.z; ub[idx + 3] = v.w;
    }

    // ---- y head: write out early, keep only (s0, x0) ----
    const float* yb = y + b * 9;                // wave-uniform -> broadcast
    float s0[8], x0;
    {
        float yv[9];
#pragma unroll
        for (int i = 0; i < 9; ++i) yv[i] = yb[i];
        if (k < 9) out[(long)b * O_ROW + k] = yv[k];
#pragma unroll
        for (int i = 0; i < 8; ++i) s0[i] = yv[i + 1] - yv[i];
        x0 = yv[8];
    }

    // ---- lane window LDS -> regs (wave-lockstep, conflict-free) ----
    float ua[40];                               // ua[0] unused
    {
        const int base = 33 * k;
#pragma unroll
        for (int j = 1; j < 40; ++j) ua[j] = ub[base + j + (j >> 5)];
    }

    // ---- phase 1: zero-state chunk recurrence ----
    float dr[8], x = 0.f;
#pragma unroll
    for (int i = 0; i < 8; ++i) dr[i] = 0.f;
#pragma unroll
    for (int s = 0; s < L_CH; ++s) {
        float acc = wu[0] * ua[s + 1];
#pragma unroll
        for (int j = 1; j < 8; ++j) acc = fmaf(wu[j], ua[s + 1 + j], acc);
#pragma unroll
        for (int j = 0; j < 8; ++j) acc = fmaf(wd[j], dr[j], acc);
#pragma unroll
        for (int j = 0; j < 7; ++j) dr[j] = dr[j + 1];
        dr[7] = acc;
        x += acc;
    }

    // ---- build level maps: T=A^L columns + sumG, then repeated squaring ----
    if (lt < 8) {
        float tr[8];
#pragma unroll
        for (int i = 0; i < 8; ++i) tr[i] = (i == lt) ? 1.f : 0.f;
        float xs = 0.f;
        for (int t = 0; t < L_CH; ++t) {
            float acc = wd[0] * tr[0];
#pragma unroll
            for (int i = 1; i < 8; ++i) acc = fmaf(wd[i], tr[i], acc);
#pragma unroll
            for (int i = 0; i < 7; ++i) tr[i] = tr[i + 1];
            tr[7] = acc; xs += acc;
        }
#pragma unroll
        for (int i = 0; i < 8; ++i) Msh[i * 8 + lt] = tr[i];  // column lt
        Csh[lt] = xs;
    }
    __syncthreads();
    for (int l = 1; l < 6; ++l) {
        const float* Mp = Msh + (l - 1) * 64;
        const float* Cp = Csh + (l - 1) * 8;
        float mv = 0.f, cv = 0.f;
        if (lt < 64) {
            const int i = lt >> 3, j = lt & 7;
            float a = 0.f;
#pragma unroll
            for (int m = 0; m < 8; ++m) a = fmaf(Mp[i * 8 + m], Mp[m * 8 + j], a);
            mv = a;
        }
        if (lt < 8) {
            float a = Cp[lt];
#pragma unroll
            for (int i = 0; i < 8; ++i) a = fmaf(Cp[i], Mp[i * 8 + lt], a);
            cv = a;
        }
        __syncthreads();
        if (lt < 64) Msh[l * 64 + lt] = mv;
        if (lt < 8)  Csh[l * 8 + lt] = cv;
        __syncthreads();
    }

    // ---- phase 2: Kogge-Stone scan of affine chunk maps across the wave ----
    float P[8], Q = x;
#pragma unroll
    for (int i = 0; i < 8; ++i) P[i] = dr[i];

    if (k == 0) {   // fold true initial state into chunk 0's result
        float np[8];
#pragma unroll
        for (int i = 0; i < 8; ++i) {
            float a = P[i];
#pragma unroll
            for (int j = 0; j < 8; ++j) a = fmaf(Msh[i * 8 + j], s0[j], a);
            np[i] = a;
        }
        float qa = Q;
#pragma unroll
        for (int j = 0; j < 8; ++j) qa = fmaf(Csh[j], s0[j], qa);
#pragma unroll
        for (int i = 0; i < 8; ++i) P[i] = np[i];
        Q = qa;
    }

#pragma unroll
    for (int l = 0; l < 6; ++l) {
        const int delta = 1 << l;
        float Pl[8], Ql;
#pragma unroll
        for (int i = 0; i < 8; ++i) Pl[i] = __shfl_up(P[i], delta);
        Ql = __shfl_up(Q, delta);
        if (k >= delta) {
            const float* Mp = Msh + l * 64;
            const float* Cp = Csh + l * 8;
            float np[8];
#pragma unroll
            for (int i = 0; i < 8; ++i) {
                float a = P[i];
#pragma unroll
                for (int j = 0; j < 8; ++j) a = fmaf(Mp[i * 8 + j], Pl[j], a);
                np[i] = a;
            }
            float qa = Q + Ql;
#pragma unroll
            for (int j = 0; j < 8; ++j) qa = fmaf(Cp[j], Pl[j], qa);
#pragma unroll
            for (int i = 0; i < 8; ++i) P[i] = np[i];
            Q = qa;
        }
    }

    // incoming state of chunk k = inclusive result of lane k-1
    float Pin[8], Qin;
#pragma unroll
    for (int i = 0; i < 8; ++i) Pin[i] = __shfl_up(P[i], 1);
    Qin = __shfl_up(Q, 1);
    if (k == 0) {
#pragma unroll
        for (int i = 0; i < 8; ++i) Pin[i] = s0[i];
        Qin = 0.f;
    }

    // ---- phase 3: true recurrence; stage x into same LDS row (u in regs) ----
#pragma unroll
    for (int i = 0; i < 8; ++i) dr[i] = Pin[i];
    x = x0 + Qin;

    const int obase = 33 * k;                   // reuse padded row for outputs
#pragma unroll
    for (int s = 0; s < L_CH; ++s) {
        float acc = wu[0] * ua[s + 1];
#pragma unroll
        for (int j = 1; j < 8; ++j) acc = fmaf(wu[j], ua[s + 1 + j], acc);
#pragma unroll
        for (int j = 0; j < 8; ++j) acc = fmaf(wd[j], dr[j], acc);
#pragma unroll
        for (int j = 0; j < 7; ++j) dr[j] = dr[j + 1];
        dr[7] = acc;
        x += acc;
        ub[obase + s] = x;
    }

    // ---- coalesced writeback: lane i <-> row position 64r + i ----
    const long orow = (long)b * O_ROW;
#pragma unroll
    for (int r = 0; r < 33; ++r) {
        const int p = r * 64 + k;
        if (p >= 9 && p < O_ROW) {
            const int g = p - 9;
            out[orow + p] = ub[g + (g >> 5)];
        }
    }
}

extern "C" void kernel_launch(void* const* d_in, const int* in_sizes, int n_in,
                              void* d_out, int out_size, void* d_ws, size_t ws_size,
                              hipStream_t stream) {
    const float* y = (const float*)d_in[0];
    const float* u = (const float*)d_in[1];
    const float* W = (const float*)d_in[2];
    float* out = (float*)d_out;

    arix_fused<<<dim3(B_TOT / 4), dim3(256), 0, stream>>>(y, u, W, out);
}